// Round 4
// baseline (367.567 us; speedup 1.0000x reference)
//
#include <hip/hip_runtime.h>

typedef _Float16 f16;
typedef _Float16 f16x4 __attribute__((ext_vector_type(4)));
typedef _Float16 f16x8 __attribute__((ext_vector_type(8)));
typedef float    f32x4 __attribute__((ext_vector_type(4)));

#define BATCH 65536
#define INDIM 512
#define MD    64
#define MSZ   100
#define NCAT  35
#define CKSZ  5
#define ODIM  512
#define NSLOT (NCAT*CKSZ)   // 175
#define RBS   232           // rb stride (f16): cols 0..227 used
#define PAS   132           // pa stride (f16): cols 0..127 used

static __device__ __forceinline__ f32x4 mfma16(f16x4 a, f16x4 b, f32x4 c) {
  return __builtin_amdgcn_mfma_f32_16x16x16f16(a, b, c, 0, 0, 0);
}

// ============ prep: fragment-packed B1p/B2p + C2cat + bias1 ============
// B1p quad idx: ((ntile*32 + kstep)*64 + lane)*4+j  = B1[ntile*16+(lane&15)][kstep*16+4*(lane>>4)+j]
//   conceptual B1 rows: n<64: W_base; n<128: W_cat; n<228: W_base^T·l2norm(keys[n-128])
// B2p quad idx: ((otile*8 + kstep)*64 + lane)*4+j  = B2[otile*16+(lane&15)][kstep*16+4*(lane>>4)+j]
//   conceptual B2[o][kk] = kk<100 ? base_vals[kk]·W_out[o,:64] : 0
// id ranges: [0,32768) B1p | [32768,49152) B2p | [49152,138752) C2cat | [138752,139008) bias1
__global__ __launch_bounds__(256) void k_prep(
    const float* __restrict__ Wb, const float* __restrict__ bb,
    const float* __restrict__ Wc, const float* __restrict__ bc,
    const float* __restrict__ keys, const float* __restrict__ bvals,
    const float* __restrict__ cvals, const float* __restrict__ Wo,
    f16* __restrict__ B1p, float* __restrict__ bias1,
    f16* __restrict__ B2p, f16* __restrict__ C2cat) {
  int id = blockIdx.x * 256 + threadIdx.x;
  if (id < 32768) {
    int l = id & 63, ntile = id >> 11;
    int n = ntile * 16 + (l & 15);
    int kb = ((id >> 6) & 31) * 16 + 4 * (l >> 4);
    float v0 = 0.f, v1 = 0.f, v2 = 0.f, v3 = 0.f;
    if (n < 64) {
      const float* w = Wb + n * INDIM + kb;
      v0 = w[0]; v1 = w[1]; v2 = w[2]; v3 = w[3];
    } else if (n < 128) {
      const float* w = Wc + (n - 64) * INDIM + kb;
      v0 = w[0]; v1 = w[1]; v2 = w[2]; v3 = w[3];
    } else if (n < 128 + MSZ) {
      int m = n - 128;
      float ss = 0.f;
      for (int d = 0; d < MD; d++) { float kv = keys[m * MD + d]; ss += kv * kv; }
      float rin = 1.f / fmaxf(sqrtf(ss), 1e-8f);
      for (int d = 0; d < MD; d++) {
        float kd = keys[m * MD + d];
        const float* wr = Wb + d * INDIM + kb;
        v0 += wr[0] * kd; v1 += wr[1] * kd; v2 += wr[2] * kd; v3 += wr[3] * kd;
      }
      v0 *= rin; v1 *= rin; v2 *= rin; v3 *= rin;
    }
    f16x4 o; o[0] = (f16)v0; o[1] = (f16)v1; o[2] = (f16)v2; o[3] = (f16)v3;
    *(f16x4*)(B1p + (size_t)id * 4) = o;
  } else if (id < 49152) {
    int q2 = id - 32768;
    int l = q2 & 63, otile = q2 >> 9;
    int o = otile * 16 + (l & 15);
    int kkb = ((q2 >> 6) & 7) * 16 + 4 * (l >> 4);
    float v0 = 0.f, v1 = 0.f, v2 = 0.f, v3 = 0.f;
    if (kkb < MSZ) {   // kkb multiple of 4; kkb<=96 -> all 4 kk valid
      for (int d = 0; d < MD; d++) {
        float w = Wo[o * 128 + d];
        v0 += bvals[(kkb + 0) * MD + d] * w;
        v1 += bvals[(kkb + 1) * MD + d] * w;
        v2 += bvals[(kkb + 2) * MD + d] * w;
        v3 += bvals[(kkb + 3) * MD + d] * w;
      }
    }
    f16x4 o4; o4[0] = (f16)v0; o4[1] = (f16)v1; o4[2] = (f16)v2; o4[3] = (f16)v3;
    *(f16x4*)(B2p + (size_t)q2 * 4) = o4;
  } else if (id < 138752) {
    int id3 = id - 49152;
    int s = id3 >> 9, o = id3 & 511;
    float a = 0.f;
    for (int d = 0; d < MD; d++) a += cvals[s * MD + d] * Wo[o * 128 + 64 + d];
    C2cat[(size_t)s * ODIM + o] = (f16)a;
  } else if (id < 139008) {
    int n = id - 138752;
    float bv = 0.f;
    if (n < 64) bv = bb[n];
    else if (n < 128) bv = bc[n - 64];
    else if (n < 128 + MSZ) {
      int m = n - 128;
      float ss = 0.f;
      for (int d = 0; d < MD; d++) { float kv = keys[m * MD + d]; ss += kv * kv; }
      float rin = 1.f / fmaxf(sqrtf(ss), 1e-8f);
      float a = 0.f;
      for (int d = 0; d < MD; d++) a += bb[d] * keys[m * MD + d];
      bv = a * rin;
    }
    bias1[n] = bv;
  }
}

// ============ fused: 2 barriers total ============
__global__ __launch_bounds__(256, 3) void k_fused(
    const float* __restrict__ q, const f16* __restrict__ B1p,
    const float* __restrict__ bias1, const int* __restrict__ cidx,
    const float* __restrict__ catk, const f16* __restrict__ B2p,
    const f16* __restrict__ C2cat, const float* __restrict__ bout,
    float* __restrict__ out) {
  __shared__ f16 rb[64][RBS];     // X rows (written p1-epi, read p2)
  __shared__ f16 pa[64][PAS];     // A2-base (written p2, read p3)
  __shared__ float cw[64][6];
  __shared__ int   cs[64];

  const int tid = threadIdx.x;
  const int lane = tid & 63, wid = tid >> 6;
  const int l15 = lane & 15, l4 = lane >> 4;
  const int row0 = blockIdx.x * 64;

  f32x4 acc[4][4];
#pragma unroll
  for (int i = 0; i < 4; i++)
#pragma unroll
    for (int j = 0; j < 4; j++) acc[i][j] = (f32x4){0.f, 0.f, 0.f, 0.f};

  // ===== phase 1: X = q @ B1^T + bias1 (no barriers; frags direct) =====
  {
    const float* qb = q + (size_t)(row0 + l15) * INDIM + 4 * l4;
    const f16* bfrag = B1p + ((size_t)(wid * 4) * 32 + 0) * 256 + (size_t)lane * 4;
    // B frag for (ni, ks): B1p + (((wid*4+ni)*32 + ks)*64 + lane)*4
#pragma unroll 4
    for (int ks = 0; ks < 32; ks++) {
      f16x4 af[4], bf[4];
#pragma unroll
      for (int mi = 0; mi < 4; mi++) {
        f32x4 a = *(const f32x4*)(qb + mi * 16 * INDIM + ks * 16);
        af[mi][0] = (f16)a[0]; af[mi][1] = (f16)a[1];
        af[mi][2] = (f16)a[2]; af[mi][3] = (f16)a[3];
      }
#pragma unroll
      for (int ni = 0; ni < 4; ni++)
        bf[ni] = *(const f16x4*)(bfrag + ((size_t)ni * 32 + ks) * 256);
#pragma unroll
      for (int mi = 0; mi < 4; mi++)
#pragma unroll
        for (int ni = 0; ni < 4; ni++)
          acc[mi][ni] = mfma16(af[mi], bf[ni], acc[mi][ni]);
    }
  }
  // epilogue -> rb (mask cols >= RBS; they're unused)
#pragma unroll
  for (int ni = 0; ni < 4; ni++) {
    const int col = wid * 64 + ni * 16 + l15;
    const float bs = bias1[col];
    if (col < RBS) {
#pragma unroll
      for (int mi = 0; mi < 4; mi++) {
        const int r = mi * 16 + 4 * l4;
#pragma unroll
        for (int j = 0; j < 4; j++)
          rb[r + j][col] = (f16)(acc[mi][ni][j] + bs);
      }
    }
  }
  __syncthreads();

  // ===== phase 2: fully-parallel softmax/mid (4 threads per row) =====
  {
    const int row = tid >> 2, s = tid & 3;
    // L2 norm of bq (cols 0..63): this thread sums 16 squares
    f16x8 v0 = *(const f16x8*)&rb[row][s * 16];
    f16x8 v1 = *(const f16x8*)&rb[row][s * 16 + 8];
    float nb = 0.f;
#pragma unroll
    for (int i = 0; i < 8; i++) { float x = (float)v0[i]; nb += x * x; }
#pragma unroll
    for (int i = 0; i < 8; i++) { float x = (float)v1[i]; nb += x * x; }
    nb += __shfl_xor(nb, 1, 64);
    nb += __shfl_xor(nb, 2, 64);
    const float rinv = 1.f / fmaxf(sqrtf(nb), 1e-8f);

    // base softmax over 100 sims (cols 128..227): 25 per thread
    float sv[25];
#pragma unroll
    for (int i = 0; i < 25; i++)
      sv[i] = (float)rb[row][128 + s * 25 + i] * rinv;
    float mx = sv[0];
#pragma unroll
    for (int i = 1; i < 25; i++) mx = fmaxf(mx, sv[i]);
    mx = fmaxf(mx, __shfl_xor(mx, 1, 64));
    mx = fmaxf(mx, __shfl_xor(mx, 2, 64));
    float es = 0.f;
#pragma unroll
    for (int i = 0; i < 25; i++) { sv[i] = __expf(sv[i] - mx); es += sv[i]; }
    es += __shfl_xor(es, 1, 64);
    es += __shfl_xor(es, 2, 64);
    const float isum = 1.f / es;
#pragma unroll
    for (int i = 0; i < 25; i++)
      pa[row][s * 25 + i] = (f16)(sv[i] * isum);
#pragma unroll
    for (int i = 0; i < 7; i++)
      pa[row][MSZ + s * 7 + i] = (f16)0.f;   // zero cols 100..127

    // category: 5 dots over cq (cols 64..127), 16 elems per thread
    const int ci = cidx[row0 + row];
    const float* kp = catk + (size_t)ci * (CKSZ * MD) + s * 16;
    f16x8 c0 = *(const f16x8*)&rb[row][64 + s * 16];
    f16x8 c1 = *(const f16x8*)&rb[row][64 + s * 16 + 8];
    float cqf[16];
#pragma unroll
    for (int i = 0; i < 8; i++) { cqf[i] = (float)c0[i]; cqf[8 + i] = (float)c1[i]; }
    float t[5];
#pragma unroll
    for (int sl = 0; sl < 5; sl++) {
      f32x4 k0 = *(const f32x4*)(kp + sl * MD);
      f32x4 k1 = *(const f32x4*)(kp + sl * MD + 4);
      f32x4 k2 = *(const f32x4*)(kp + sl * MD + 8);
      f32x4 k3 = *(const f32x4*)(kp + sl * MD + 12);
      float a = 0.f;
#pragma unroll
      for (int i = 0; i < 4; i++) a += cqf[i] * k0[i];
#pragma unroll
      for (int i = 0; i < 4; i++) a += cqf[4 + i] * k1[i];
#pragma unroll
      for (int i = 0; i < 4; i++) a += cqf[8 + i] * k2[i];
#pragma unroll
      for (int i = 0; i < 4; i++) a += cqf[12 + i] * k3[i];
      a += __shfl_xor(a, 1, 64);
      a += __shfl_xor(a, 2, 64);
      t[sl] = a;
    }
    if (s == 0) {
      float m5 = fmaxf(fmaxf(fmaxf(t[0], t[1]), fmaxf(t[2], t[3])), t[4]);
      float e0 = __expf(t[0] - m5), e1 = __expf(t[1] - m5), e2 = __expf(t[2] - m5),
            e3 = __expf(t[3] - m5), e4 = __expf(t[4] - m5);
      float ics = 1.f / (e0 + e1 + e2 + e3 + e4);
      cw[row][0] = e0 * ics; cw[row][1] = e1 * ics; cw[row][2] = e2 * ics;
      cw[row][3] = e3 * ics; cw[row][4] = e4 * ics;
      cs[row] = ci * CKSZ;
    }
  }
  __syncthreads();

  // ===== phase 3: out = pa @ B2^T + bout + rank-5 cat gather (no barriers)
  for (int cpass = 0; cpass < 2; cpass++) {
#pragma unroll
    for (int i = 0; i < 4; i++)
#pragma unroll
      for (int j = 0; j < 4; j++) acc[i][j] = (f32x4){0.f, 0.f, 0.f, 0.f};
    const f16* bfrag2 = B2p + ((size_t)(cpass * 16 + wid * 4) * 8) * 256 + (size_t)lane * 4;
#pragma unroll
    for (int ks = 0; ks < 8; ks++) {
      f16x4 af[4], bf[4];
#pragma unroll
      for (int mi = 0; mi < 4; mi++)
        af[mi] = *(const f16x4*)&pa[mi * 16 + l15][ks * 16 + 4 * l4];
#pragma unroll
      for (int ni = 0; ni < 4; ni++)
        bf[ni] = *(const f16x4*)(bfrag2 + ((size_t)ni * 8 + ks) * 256);
#pragma unroll
      for (int mi = 0; mi < 4; mi++)
#pragma unroll
        for (int ni = 0; ni < 4; ni++)
          acc[mi][ni] = mfma16(af[mi], bf[ni], acc[mi][ni]);
    }
    // epilogue: bias + rank-5 category gather + store
    float bs[4];
#pragma unroll
    for (int ni = 0; ni < 4; ni++) bs[ni] = bout[cpass * 256 + wid * 64 + ni * 16 + l15];
#pragma unroll
    for (int mi = 0; mi < 4; mi++) {
#pragma unroll
      for (int j = 0; j < 4; j++) {
        const int r = mi * 16 + 4 * l4 + j;
        const int cb = cs[r];
        const float w0 = cw[r][0], w1 = cw[r][1], w2 = cw[r][2],
                    w3 = cw[r][3], w4 = cw[r][4];
        const f16* cp = C2cat + (size_t)cb * ODIM + cpass * 256 + wid * 64 + l15;
#pragma unroll
        for (int ni = 0; ni < 4; ni++) {
          const int col = cpass * 256 + wid * 64 + ni * 16 + l15;
          const f16* cpn = cp + ni * 16;
          float v = acc[mi][ni][j] + bs[ni];
          v += w0 * (float)cpn[0]
             + w1 * (float)cpn[ODIM]
             + w2 * (float)cpn[2 * ODIM]
             + w3 * (float)cpn[3 * ODIM]
             + w4 * (float)cpn[4 * ODIM];
          out[(size_t)(row0 + r) * ODIM + col] = v;
        }
      }
    }
  }
}

extern "C" void kernel_launch(void* const* d_in, const int* in_sizes, int n_in,
                              void* d_out, int out_size, void* d_ws, size_t ws_size,
                              hipStream_t stream) {
  const float* query = (const float*)d_in[0];
  const int*   cidx  = (const int*)d_in[1];
  const float* Wb    = (const float*)d_in[2];
  const float* bb    = (const float*)d_in[3];
  const float* Wc    = (const float*)d_in[4];
  const float* bc    = (const float*)d_in[5];
  const float* bkeys = (const float*)d_in[6];
  const float* bvals = (const float*)d_in[7];
  const float* ckeys = (const float*)d_in[8];
  const float* cvals = (const float*)d_in[9];
  const float* Wo    = (const float*)d_in[10];
  const float* bo    = (const float*)d_in[11];
  float* out = (float*)d_out;

  char* ws = (char*)d_ws;
  f16*   B1p   = (f16*)(ws);                        // 32768*4*2  = 262144
  f16*   B2p   = (f16*)(ws + 262144);               // 16384*4*2  = 131072
  f16*   C2cat = (f16*)(ws + 262144 + 131072);      // 175*512*2  = 179200
  float* bias1 = (float*)(ws + 262144 + 131072 + 179200);  // 1024

  k_prep<<<dim3((139008 + 255) / 256), 256, 0, stream>>>(
      Wb, bb, Wc, bc, bkeys, bvals, cvals, Wo, B1p, bias1, B2p, C2cat);
  k_fused<<<dim3(BATCH / 64), 256, 0, stream>>>(
      query, B1p, bias1, cidx, ckeys, B2p, C2cat, bo, out);
}

// Round 5
// 367.205 us; speedup vs baseline: 1.0010x; 1.0010x over previous
//
#include <hip/hip_runtime.h>

typedef _Float16 f16;
typedef _Float16 f16x4 __attribute__((ext_vector_type(4)));
typedef _Float16 f16x8 __attribute__((ext_vector_type(8)));
typedef float    f32x4 __attribute__((ext_vector_type(4)));

#define BATCH 65536
#define INDIM 512
#define MD    64
#define MSZ   100
#define NCAT  35
#define CKSZ  5
#define ODIM  512
#define NSLOT (NCAT*CKSZ)   // 175
#define RBS   232           // rb stride (f16): cols 0..227 used
#define PAS   132           // pa stride (f16): cols 0..127 used

static __device__ __forceinline__ f32x4 mfma16(f16x4 a, f16x4 b, f32x4 c) {
  return __builtin_amdgcn_mfma_f32_16x16x16f16(a, b, c, 0, 0, 0);
}

// ============ prep: fragment-packed B1p/B2p + C2cat + bias1 ============
// B1p quad idx: ((ntile*32 + kstep)*64 + lane)*4+j  = B1[ntile*16+(lane&15)][kstep*16+4*(lane>>4)+j]
//   conceptual B1 rows: n<64: W_base; n<128: W_cat; n<228: W_base^T·l2norm(keys[n-128])
// B2p quad idx: ((otile*8 + kstep)*64 + lane)*4+j  = B2[otile*16+(lane&15)][kstep*16+4*(lane>>4)+j]
//   conceptual B2[o][kk] = kk<100 ? base_vals[kk]·W_out[o,:64] : 0
// id ranges: [0,32768) B1p | [32768,49152) B2p | [49152,138752) C2cat | [138752,139008) bias1
__global__ __launch_bounds__(256) void k_prep(
    const float* __restrict__ Wb, const float* __restrict__ bb,
    const float* __restrict__ Wc, const float* __restrict__ bc,
    const float* __restrict__ keys, const float* __restrict__ bvals,
    const float* __restrict__ cvals, const float* __restrict__ Wo,
    f16* __restrict__ B1p, float* __restrict__ bias1,
    f16* __restrict__ B2p, f16* __restrict__ C2cat) {
  int id = blockIdx.x * 256 + threadIdx.x;
  if (id < 32768) {
    int l = id & 63, ntile = id >> 11;
    int n = ntile * 16 + (l & 15);
    int kb = ((id >> 6) & 31) * 16 + 4 * (l >> 4);
    float v0 = 0.f, v1 = 0.f, v2 = 0.f, v3 = 0.f;
    if (n < 64) {
      const float* w = Wb + n * INDIM + kb;
      v0 = w[0]; v1 = w[1]; v2 = w[2]; v3 = w[3];
    } else if (n < 128) {
      const float* w = Wc + (n - 64) * INDIM + kb;
      v0 = w[0]; v1 = w[1]; v2 = w[2]; v3 = w[3];
    } else if (n < 128 + MSZ) {
      int m = n - 128;
      float ss = 0.f;
      for (int d = 0; d < MD; d++) { float kv = keys[m * MD + d]; ss += kv * kv; }
      float rin = 1.f / fmaxf(sqrtf(ss), 1e-8f);
      for (int d = 0; d < MD; d++) {
        float kd = keys[m * MD + d];
        const float* wr = Wb + d * INDIM + kb;
        v0 += wr[0] * kd; v1 += wr[1] * kd; v2 += wr[2] * kd; v3 += wr[3] * kd;
      }
      v0 *= rin; v1 *= rin; v2 *= rin; v3 *= rin;
    }
    f16x4 o; o[0] = (f16)v0; o[1] = (f16)v1; o[2] = (f16)v2; o[3] = (f16)v3;
    *(f16x4*)(B1p + (size_t)id * 4) = o;
  } else if (id < 49152) {
    int q2 = id - 32768;
    int l = q2 & 63, otile = q2 >> 9;
    int o = otile * 16 + (l & 15);
    int kkb = ((q2 >> 6) & 7) * 16 + 4 * (l >> 4);
    float v0 = 0.f, v1 = 0.f, v2 = 0.f, v3 = 0.f;
    if (kkb < MSZ) {   // kkb multiple of 4; kkb<=96 -> all 4 kk valid
      for (int d = 0; d < MD; d++) {
        float w = Wo[o * 128 + d];
        v0 += bvals[(kkb + 0) * MD + d] * w;
        v1 += bvals[(kkb + 1) * MD + d] * w;
        v2 += bvals[(kkb + 2) * MD + d] * w;
        v3 += bvals[(kkb + 3) * MD + d] * w;
      }
    }
    f16x4 o4; o4[0] = (f16)v0; o4[1] = (f16)v1; o4[2] = (f16)v2; o4[3] = (f16)v3;
    *(f16x4*)(B2p + (size_t)q2 * 4) = o4;
  } else if (id < 138752) {
    int id3 = id - 49152;
    int s = id3 >> 9, o = id3 & 511;
    float a = 0.f;
    for (int d = 0; d < MD; d++) a += cvals[s * MD + d] * Wo[o * 128 + 64 + d];
    C2cat[(size_t)s * ODIM + o] = (f16)a;
  } else if (id < 139008) {
    int n = id - 138752;
    float bv = 0.f;
    if (n < 64) bv = bb[n];
    else if (n < 128) bv = bc[n - 64];
    else if (n < 128 + MSZ) {
      int m = n - 128;
      float ss = 0.f;
      for (int d = 0; d < MD; d++) { float kv = keys[m * MD + d]; ss += kv * kv; }
      float rin = 1.f / fmaxf(sqrtf(ss), 1e-8f);
      float a = 0.f;
      for (int d = 0; d < MD; d++) a += bb[d] * keys[m * MD + d];
      bv = a * rin;
    }
    bias1[n] = bv;
  }
}

// ============ fused: 2 barriers total ============
__global__ __launch_bounds__(256, 3) void k_fused(
    const float* __restrict__ q, const f16* __restrict__ B1p,
    const float* __restrict__ bias1, const int* __restrict__ cidx,
    const float* __restrict__ catk, const f16* __restrict__ B2p,
    const f16* __restrict__ C2cat, const float* __restrict__ bout,
    float* __restrict__ out) {
  __shared__ f16 rb[64][RBS];     // X rows (written p1-epi, read p2)
  __shared__ f16 pa[64][PAS];     // A2-base (written p2, read p3)
  __shared__ float cw[64][6];
  __shared__ int   cs[64];

  const int tid = threadIdx.x;
  const int lane = tid & 63, wid = tid >> 6;
  const int l15 = lane & 15, l4 = lane >> 4;
  const int row0 = blockIdx.x * 64;

  f32x4 acc[4][4];
#pragma unroll
  for (int i = 0; i < 4; i++)
#pragma unroll
    for (int j = 0; j < 4; j++) acc[i][j] = (f32x4){0.f, 0.f, 0.f, 0.f};

  // ===== phase 1: X = q @ B1^T + bias1 (no barriers; frags direct) =====
  {
    const float* qb = q + (size_t)(row0 + l15) * INDIM + 4 * l4;
    const f16* bfrag = B1p + ((size_t)(wid * 4) * 32 + 0) * 256 + (size_t)lane * 4;
    // B frag for (ni, ks): B1p + (((wid*4+ni)*32 + ks)*64 + lane)*4
#pragma unroll 4
    for (int ks = 0; ks < 32; ks++) {
      f16x4 af[4], bf[4];
#pragma unroll
      for (int mi = 0; mi < 4; mi++) {
        f32x4 a = *(const f32x4*)(qb + mi * 16 * INDIM + ks * 16);
        af[mi][0] = (f16)a[0]; af[mi][1] = (f16)a[1];
        af[mi][2] = (f16)a[2]; af[mi][3] = (f16)a[3];
      }
#pragma unroll
      for (int ni = 0; ni < 4; ni++)
        bf[ni] = *(const f16x4*)(bfrag + ((size_t)ni * 32 + ks) * 256);
#pragma unroll
      for (int mi = 0; mi < 4; mi++)
#pragma unroll
        for (int ni = 0; ni < 4; ni++)
          acc[mi][ni] = mfma16(af[mi], bf[ni], acc[mi][ni]);
    }
  }
  // epilogue -> rb (mask cols >= RBS; they're unused)
#pragma unroll
  for (int ni = 0; ni < 4; ni++) {
    const int col = wid * 64 + ni * 16 + l15;
    const float bs = bias1[col];
    if (col < RBS) {
#pragma unroll
      for (int mi = 0; mi < 4; mi++) {
        const int r = mi * 16 + 4 * l4;
#pragma unroll
        for (int j = 0; j < 4; j++)
          rb[r + j][col] = (f16)(acc[mi][ni][j] + bs);
      }
    }
  }
  __syncthreads();

  // ===== phase 2: fully-parallel softmax/mid (4 threads per row) =====
  {
    const int row = tid >> 2, s = tid & 3;
    // L2 norm of bq (cols 0..63): this thread sums 16 squares
    f16x8 v0 = *(const f16x8*)&rb[row][s * 16];
    f16x8 v1 = *(const f16x8*)&rb[row][s * 16 + 8];
    float nb = 0.f;
#pragma unroll
    for (int i = 0; i < 8; i++) { float x = (float)v0[i]; nb += x * x; }
#pragma unroll
    for (int i = 0; i < 8; i++) { float x = (float)v1[i]; nb += x * x; }
    nb += __shfl_xor(nb, 1, 64);
    nb += __shfl_xor(nb, 2, 64);
    const float rinv = 1.f / fmaxf(sqrtf(nb), 1e-8f);

    // base softmax over 100 sims (cols 128..227): 25 per thread
    float sv[25];
#pragma unroll
    for (int i = 0; i < 25; i++)
      sv[i] = (float)rb[row][128 + s * 25 + i] * rinv;
    float mx = sv[0];
#pragma unroll
    for (int i = 1; i < 25; i++) mx = fmaxf(mx, sv[i]);
    mx = fmaxf(mx, __shfl_xor(mx, 1, 64));
    mx = fmaxf(mx, __shfl_xor(mx, 2, 64));
    float es = 0.f;
#pragma unroll
    for (int i = 0; i < 25; i++) { sv[i] = __expf(sv[i] - mx); es += sv[i]; }
    es += __shfl_xor(es, 1, 64);
    es += __shfl_xor(es, 2, 64);
    const float isum = 1.f / es;
#pragma unroll
    for (int i = 0; i < 25; i++)
      pa[row][s * 25 + i] = (f16)(sv[i] * isum);
#pragma unroll
    for (int i = 0; i < 7; i++)
      pa[row][MSZ + s * 7 + i] = (f16)0.f;   // zero cols 100..127

    // category: 5 dots over cq (cols 64..127), 16 elems per thread
    const int ci = cidx[row0 + row];
    const float* kp = catk + (size_t)ci * (CKSZ * MD) + s * 16;
    f16x8 c0 = *(const f16x8*)&rb[row][64 + s * 16];
    f16x8 c1 = *(const f16x8*)&rb[row][64 + s * 16 + 8];
    float cqf[16];
#pragma unroll
    for (int i = 0; i < 8; i++) { cqf[i] = (float)c0[i]; cqf[8 + i] = (float)c1[i]; }
    float t[5];
#pragma unroll
    for (int sl = 0; sl < 5; sl++) {
      f32x4 k0 = *(const f32x4*)(kp + sl * MD);
      f32x4 k1 = *(const f32x4*)(kp + sl * MD + 4);
      f32x4 k2 = *(const f32x4*)(kp + sl * MD + 8);
      f32x4 k3 = *(const f32x4*)(kp + sl * MD + 12);
      float a = 0.f;
#pragma unroll
      for (int i = 0; i < 4; i++) a += cqf[i] * k0[i];
#pragma unroll
      for (int i = 0; i < 4; i++) a += cqf[4 + i] * k1[i];
#pragma unroll
      for (int i = 0; i < 4; i++) a += cqf[8 + i] * k2[i];
#pragma unroll
      for (int i = 0; i < 4; i++) a += cqf[12 + i] * k3[i];
      a += __shfl_xor(a, 1, 64);
      a += __shfl_xor(a, 2, 64);
      t[sl] = a;
    }
    if (s == 0) {
      float m5 = fmaxf(fmaxf(fmaxf(t[0], t[1]), fmaxf(t[2], t[3])), t[4]);
      float e0 = __expf(t[0] - m5), e1 = __expf(t[1] - m5), e2 = __expf(t[2] - m5),
            e3 = __expf(t[3] - m5), e4 = __expf(t[4] - m5);
      float ics = 1.f / (e0 + e1 + e2 + e3 + e4);
      cw[row][0] = e0 * ics; cw[row][1] = e1 * ics; cw[row][2] = e2 * ics;
      cw[row][3] = e3 * ics; cw[row][4] = e4 * ics;
      cs[row] = ci * CKSZ;
    }
  }
  __syncthreads();

  // ===== phase 3: out = pa @ B2^T + bout + rank-5 cat gather (no barriers)
  for (int cpass = 0; cpass < 2; cpass++) {
#pragma unroll
    for (int i = 0; i < 4; i++)
#pragma unroll
      for (int j = 0; j < 4; j++) acc[i][j] = (f32x4){0.f, 0.f, 0.f, 0.f};
    const f16* bfrag2 = B2p + ((size_t)(cpass * 16 + wid * 4) * 8) * 256 + (size_t)lane * 4;
#pragma unroll
    for (int ks = 0; ks < 8; ks++) {
      f16x4 af[4], bf[4];
#pragma unroll
      for (int mi = 0; mi < 4; mi++)
        af[mi] = *(const f16x4*)&pa[mi * 16 + l15][ks * 16 + 4 * l4];
#pragma unroll
      for (int ni = 0; ni < 4; ni++)
        bf[ni] = *(const f16x4*)(bfrag2 + ((size_t)ni * 8 + ks) * 256);
#pragma unroll
      for (int mi = 0; mi < 4; mi++)
#pragma unroll
        for (int ni = 0; ni < 4; ni++)
          acc[mi][ni] = mfma16(af[mi], bf[ni], acc[mi][ni]);
    }
    // epilogue: bias + rank-5 category gather + store
    float bs[4];
#pragma unroll
    for (int ni = 0; ni < 4; ni++) bs[ni] = bout[cpass * 256 + wid * 64 + ni * 16 + l15];
#pragma unroll
    for (int mi = 0; mi < 4; mi++) {
#pragma unroll
      for (int j = 0; j < 4; j++) {
        const int r = mi * 16 + 4 * l4 + j;
        const int cb = cs[r];
        const float w0 = cw[r][0], w1 = cw[r][1], w2 = cw[r][2],
                    w3 = cw[r][3], w4 = cw[r][4];
        const f16* cp = C2cat + (size_t)cb * ODIM + cpass * 256 + wid * 64 + l15;
#pragma unroll
        for (int ni = 0; ni < 4; ni++) {
          const int col = cpass * 256 + wid * 64 + ni * 16 + l15;
          const f16* cpn = cp + ni * 16;
          float v = acc[mi][ni][j] + bs[ni];
          v += w0 * (float)cpn[0]
             + w1 * (float)cpn[ODIM]
             + w2 * (float)cpn[2 * ODIM]
             + w3 * (float)cpn[3 * ODIM]
             + w4 * (float)cpn[4 * ODIM];
          out[(size_t)(row0 + r) * ODIM + col] = v;
        }
      }
    }
  }
}

extern "C" void kernel_launch(void* const* d_in, const int* in_sizes, int n_in,
                              void* d_out, int out_size, void* d_ws, size_t ws_size,
                              hipStream_t stream) {
  const float* query = (const float*)d_in[0];
  const int*   cidx  = (const int*)d_in[1];
  const float* Wb    = (const float*)d_in[2];
  const float* bb    = (const float*)d_in[3];
  const float* Wc    = (const float*)d_in[4];
  const float* bc    = (const float*)d_in[5];
  const float* bkeys = (const float*)d_in[6];
  const float* bvals = (const float*)d_in[7];
  const float* ckeys = (const float*)d_in[8];
  const float* cvals = (const float*)d_in[9];
  const float* Wo    = (const float*)d_in[10];
  const float* bo    = (const float*)d_in[11];
  float* out = (float*)d_out;

  char* ws = (char*)d_ws;
  f16*   B1p   = (f16*)(ws);                        // 32768*4*2  = 262144
  f16*   B2p   = (f16*)(ws + 262144);               // 16384*4*2  = 131072
  f16*   C2cat = (f16*)(ws + 262144 + 131072);      // 175*512*2  = 179200
  float* bias1 = (float*)(ws + 262144 + 131072 + 179200);  // 1024

  k_prep<<<dim3((139008 + 255) / 256), 256, 0, stream>>>(
      Wb, bb, Wc, bc, bkeys, bvals, cvals, Wo, B1p, bias1, B2p, C2cat);
  k_fused<<<dim3(BATCH / 64), 256, 0, stream>>>(
      query, B1p, bias1, cidx, ckeys, B2p, C2cat, bo, out);
}

// Round 6
// 366.507 us; speedup vs baseline: 1.0029x; 1.0019x over previous
//
#include <hip/hip_runtime.h>

typedef _Float16 f16;
typedef _Float16 f16x4 __attribute__((ext_vector_type(4)));
typedef _Float16 f16x8 __attribute__((ext_vector_type(8)));
typedef float    f32x4 __attribute__((ext_vector_type(4)));

#define BATCH 65536
#define INDIM 512
#define MD    64
#define MSZ   100
#define NCAT  35
#define CKSZ  5
#define ODIM  512
#define NSLOT (NCAT*CKSZ)   // 175
#define RBS   232           // rb stride (f16): cols 0..227 used
#define PAS   132           // pa stride (f16): cols 0..127 used

static __device__ __forceinline__ f32x4 mfma16(f16x4 a, f16x4 b, f32x4 c) {
  return __builtin_amdgcn_mfma_f32_16x16x16f16(a, b, c, 0, 0, 0);
}

// ============ prep: fragment-packed B1p/B2p + C2cat + bias1 ============
// B1p quad idx: ((ntile*32 + kstep)*64 + lane)*4+j  = B1[ntile*16+(lane&15)][kstep*16+4*(lane>>4)+j]
//   conceptual B1 rows: n<64: W_base; n<128: W_cat; n<228: W_base^T·l2norm(keys[n-128])
// B2p quad idx: ((otile*8 + kstep)*64 + lane)*4+j  = B2[otile*16+(lane&15)][kstep*16+4*(lane>>4)+j]
//   conceptual B2[o][kk] = kk<100 ? base_vals[kk]·W_out[o,:64] : 0
// id ranges: [0,32768) B1p | [32768,49152) B2p | [49152,138752) C2cat | [138752,139008) bias1
__global__ __launch_bounds__(256) void k_prep(
    const float* __restrict__ Wb, const float* __restrict__ bb,
    const float* __restrict__ Wc, const float* __restrict__ bc,
    const float* __restrict__ keys, const float* __restrict__ bvals,
    const float* __restrict__ cvals, const float* __restrict__ Wo,
    f16* __restrict__ B1p, float* __restrict__ bias1,
    f16* __restrict__ B2p, f16* __restrict__ C2cat) {
  int id = blockIdx.x * 256 + threadIdx.x;
  if (id < 32768) {
    int l = id & 63, ntile = id >> 11;
    int n = ntile * 16 + (l & 15);
    int kb = ((id >> 6) & 31) * 16 + 4 * (l >> 4);
    float v0 = 0.f, v1 = 0.f, v2 = 0.f, v3 = 0.f;
    if (n < 64) {
      const float* w = Wb + n * INDIM + kb;
      v0 = w[0]; v1 = w[1]; v2 = w[2]; v3 = w[3];
    } else if (n < 128) {
      const float* w = Wc + (n - 64) * INDIM + kb;
      v0 = w[0]; v1 = w[1]; v2 = w[2]; v3 = w[3];
    } else if (n < 128 + MSZ) {
      int m = n - 128;
      float ss = 0.f;
      for (int d = 0; d < MD; d++) { float kv = keys[m * MD + d]; ss += kv * kv; }
      float rin = 1.f / fmaxf(sqrtf(ss), 1e-8f);
      for (int d = 0; d < MD; d++) {
        float kd = keys[m * MD + d];
        const float* wr = Wb + d * INDIM + kb;
        v0 += wr[0] * kd; v1 += wr[1] * kd; v2 += wr[2] * kd; v3 += wr[3] * kd;
      }
      v0 *= rin; v1 *= rin; v2 *= rin; v3 *= rin;
    }
    f16x4 o; o[0] = (f16)v0; o[1] = (f16)v1; o[2] = (f16)v2; o[3] = (f16)v3;
    *(f16x4*)(B1p + (size_t)id * 4) = o;
  } else if (id < 49152) {
    int q2 = id - 32768;
    int l = q2 & 63, otile = q2 >> 9;
    int o = otile * 16 + (l & 15);
    int kkb = ((q2 >> 6) & 7) * 16 + 4 * (l >> 4);
    float v0 = 0.f, v1 = 0.f, v2 = 0.f, v3 = 0.f;
    if (kkb < MSZ) {   // kkb multiple of 4; kkb<=96 -> all 4 kk valid
      for (int d = 0; d < MD; d++) {
        float w = Wo[o * 128 + d];
        v0 += bvals[(kkb + 0) * MD + d] * w;
        v1 += bvals[(kkb + 1) * MD + d] * w;
        v2 += bvals[(kkb + 2) * MD + d] * w;
        v3 += bvals[(kkb + 3) * MD + d] * w;
      }
    }
    f16x4 o4; o4[0] = (f16)v0; o4[1] = (f16)v1; o4[2] = (f16)v2; o4[3] = (f16)v3;
    *(f16x4*)(B2p + (size_t)q2 * 4) = o4;
  } else if (id < 138752) {
    int id3 = id - 49152;
    int s = id3 >> 9, o = id3 & 511;
    float a = 0.f;
    for (int d = 0; d < MD; d++) a += cvals[s * MD + d] * Wo[o * 128 + 64 + d];
    C2cat[(size_t)s * ODIM + o] = (f16)a;
  } else if (id < 139008) {
    int n = id - 138752;
    float bv = 0.f;
    if (n < 64) bv = bb[n];
    else if (n < 128) bv = bc[n - 64];
    else if (n < 128 + MSZ) {
      int m = n - 128;
      float ss = 0.f;
      for (int d = 0; d < MD; d++) { float kv = keys[m * MD + d]; ss += kv * kv; }
      float rin = 1.f / fmaxf(sqrtf(ss), 1e-8f);
      float a = 0.f;
      for (int d = 0; d < MD; d++) a += bb[d] * keys[m * MD + d];
      bv = a * rin;
    }
    bias1[n] = bv;
  }
}

// ============ fused: 2 barriers total ============
__global__ __launch_bounds__(256, 3) void k_fused(
    const float* __restrict__ q, const f16* __restrict__ B1p,
    const float* __restrict__ bias1, const int* __restrict__ cidx,
    const float* __restrict__ catk, const f16* __restrict__ B2p,
    const f16* __restrict__ C2cat, const float* __restrict__ bout,
    float* __restrict__ out) {
  __shared__ f16 rb[64][RBS];     // X rows (written p1-epi, read p2)
  __shared__ f16 pa[64][PAS];     // A2-base (written p2, read p3)
  __shared__ float cw[64][6];
  __shared__ int   cs[64];

  const int tid = threadIdx.x;
  const int lane = tid & 63, wid = tid >> 6;
  const int l15 = lane & 15, l4 = lane >> 4;
  const int row0 = blockIdx.x * 64;

  f32x4 acc[4][4];
#pragma unroll
  for (int i = 0; i < 4; i++)
#pragma unroll
    for (int j = 0; j < 4; j++) acc[i][j] = (f32x4){0.f, 0.f, 0.f, 0.f};

  // ===== phase 1: X = q @ B1^T + bias1 (no barriers; frags direct) =====
  {
    const float* qb = q + (size_t)(row0 + l15) * INDIM + 4 * l4;
    const f16* bfrag = B1p + ((size_t)(wid * 4) * 32 + 0) * 256 + (size_t)lane * 4;
    // B frag for (ni, ks): B1p + (((wid*4+ni)*32 + ks)*64 + lane)*4
#pragma unroll 4
    for (int ks = 0; ks < 32; ks++) {
      f16x4 af[4], bf[4];
#pragma unroll
      for (int mi = 0; mi < 4; mi++) {
        f32x4 a = *(const f32x4*)(qb + mi * 16 * INDIM + ks * 16);
        af[mi][0] = (f16)a[0]; af[mi][1] = (f16)a[1];
        af[mi][2] = (f16)a[2]; af[mi][3] = (f16)a[3];
      }
#pragma unroll
      for (int ni = 0; ni < 4; ni++)
        bf[ni] = *(const f16x4*)(bfrag + ((size_t)ni * 32 + ks) * 256);
#pragma unroll
      for (int mi = 0; mi < 4; mi++)
#pragma unroll
        for (int ni = 0; ni < 4; ni++)
          acc[mi][ni] = mfma16(af[mi], bf[ni], acc[mi][ni]);
    }
  }
  // epilogue -> rb (mask cols >= RBS; they're unused)
#pragma unroll
  for (int ni = 0; ni < 4; ni++) {
    const int col = wid * 64 + ni * 16 + l15;
    const float bs = bias1[col];
    if (col < RBS) {
#pragma unroll
      for (int mi = 0; mi < 4; mi++) {
        const int r = mi * 16 + 4 * l4;
#pragma unroll
        for (int j = 0; j < 4; j++)
          rb[r + j][col] = (f16)(acc[mi][ni][j] + bs);
      }
    }
  }
  __syncthreads();

  // ===== phase 2: fully-parallel softmax/mid (4 threads per row) =====
  {
    const int row = tid >> 2, s = tid & 3;
    // L2 norm of bq (cols 0..63): this thread sums 16 squares
    f16x8 v0 = *(const f16x8*)&rb[row][s * 16];
    f16x8 v1 = *(const f16x8*)&rb[row][s * 16 + 8];
    float nb = 0.f;
#pragma unroll
    for (int i = 0; i < 8; i++) { float x = (float)v0[i]; nb += x * x; }
#pragma unroll
    for (int i = 0; i < 8; i++) { float x = (float)v1[i]; nb += x * x; }
    nb += __shfl_xor(nb, 1, 64);
    nb += __shfl_xor(nb, 2, 64);
    const float rinv = 1.f / fmaxf(sqrtf(nb), 1e-8f);

    // base softmax over 100 sims (cols 128..227): 25 per thread
    float sv[25];
#pragma unroll
    for (int i = 0; i < 25; i++)
      sv[i] = (float)rb[row][128 + s * 25 + i] * rinv;
    float mx = sv[0];
#pragma unroll
    for (int i = 1; i < 25; i++) mx = fmaxf(mx, sv[i]);
    mx = fmaxf(mx, __shfl_xor(mx, 1, 64));
    mx = fmaxf(mx, __shfl_xor(mx, 2, 64));
    float es = 0.f;
#pragma unroll
    for (int i = 0; i < 25; i++) { sv[i] = __expf(sv[i] - mx); es += sv[i]; }
    es += __shfl_xor(es, 1, 64);
    es += __shfl_xor(es, 2, 64);
    const float isum = 1.f / es;
#pragma unroll
    for (int i = 0; i < 25; i++)
      pa[row][s * 25 + i] = (f16)(sv[i] * isum);
#pragma unroll
    for (int i = 0; i < 7; i++)
      pa[row][MSZ + s * 7 + i] = (f16)0.f;   // zero cols 100..127

    // category: 5 dots over cq (cols 64..127), 16 elems per thread
    const int ci = cidx[row0 + row];
    const float* kp = catk + (size_t)ci * (CKSZ * MD) + s * 16;
    f16x8 c0 = *(const f16x8*)&rb[row][64 + s * 16];
    f16x8 c1 = *(const f16x8*)&rb[row][64 + s * 16 + 8];
    float cqf[16];
#pragma unroll
    for (int i = 0; i < 8; i++) { cqf[i] = (float)c0[i]; cqf[8 + i] = (float)c1[i]; }
    float t[5];
#pragma unroll
    for (int sl = 0; sl < 5; sl++) {
      f32x4 k0 = *(const f32x4*)(kp + sl * MD);
      f32x4 k1 = *(const f32x4*)(kp + sl * MD + 4);
      f32x4 k2 = *(const f32x4*)(kp + sl * MD + 8);
      f32x4 k3 = *(const f32x4*)(kp + sl * MD + 12);
      float a = 0.f;
#pragma unroll
      for (int i = 0; i < 4; i++) a += cqf[i] * k0[i];
#pragma unroll
      for (int i = 0; i < 4; i++) a += cqf[4 + i] * k1[i];
#pragma unroll
      for (int i = 0; i < 4; i++) a += cqf[8 + i] * k2[i];
#pragma unroll
      for (int i = 0; i < 4; i++) a += cqf[12 + i] * k3[i];
      a += __shfl_xor(a, 1, 64);
      a += __shfl_xor(a, 2, 64);
      t[sl] = a;
    }
    if (s == 0) {
      float m5 = fmaxf(fmaxf(fmaxf(t[0], t[1]), fmaxf(t[2], t[3])), t[4]);
      float e0 = __expf(t[0] - m5), e1 = __expf(t[1] - m5), e2 = __expf(t[2] - m5),
            e3 = __expf(t[3] - m5), e4 = __expf(t[4] - m5);
      float ics = 1.f / (e0 + e1 + e2 + e3 + e4);
      cw[row][0] = e0 * ics; cw[row][1] = e1 * ics; cw[row][2] = e2 * ics;
      cw[row][3] = e3 * ics; cw[row][4] = e4 * ics;
      cs[row] = ci * CKSZ;
    }
  }
  __syncthreads();

  // ===== phase 3: out = pa @ B2^T + bout + rank-5 cat gather (no barriers)
  for (int cpass = 0; cpass < 2; cpass++) {
#pragma unroll
    for (int i = 0; i < 4; i++)
#pragma unroll
      for (int j = 0; j < 4; j++) acc[i][j] = (f32x4){0.f, 0.f, 0.f, 0.f};
    const f16* bfrag2 = B2p + ((size_t)(cpass * 16 + wid * 4) * 8) * 256 + (size_t)lane * 4;
#pragma unroll
    for (int ks = 0; ks < 8; ks++) {
      f16x4 af[4], bf[4];
#pragma unroll
      for (int mi = 0; mi < 4; mi++)
        af[mi] = *(const f16x4*)&pa[mi * 16 + l15][ks * 16 + 4 * l4];
#pragma unroll
      for (int ni = 0; ni < 4; ni++)
        bf[ni] = *(const f16x4*)(bfrag2 + ((size_t)ni * 8 + ks) * 256);
#pragma unroll
      for (int mi = 0; mi < 4; mi++)
#pragma unroll
        for (int ni = 0; ni < 4; ni++)
          acc[mi][ni] = mfma16(af[mi], bf[ni], acc[mi][ni]);
    }
    // epilogue: bias + rank-5 category gather + store
    float bs[4];
#pragma unroll
    for (int ni = 0; ni < 4; ni++) bs[ni] = bout[cpass * 256 + wid * 64 + ni * 16 + l15];
#pragma unroll
    for (int mi = 0; mi < 4; mi++) {
#pragma unroll
      for (int j = 0; j < 4; j++) {
        const int r = mi * 16 + 4 * l4 + j;
        const int cb = cs[r];
        const float w0 = cw[r][0], w1 = cw[r][1], w2 = cw[r][2],
                    w3 = cw[r][3], w4 = cw[r][4];
        const f16* cp = C2cat + (size_t)cb * ODIM + cpass * 256 + wid * 64 + l15;
#pragma unroll
        for (int ni = 0; ni < 4; ni++) {
          const int col = cpass * 256 + wid * 64 + ni * 16 + l15;
          const f16* cpn = cp + ni * 16;
          float v = acc[mi][ni][j] + bs[ni];
          v += w0 * (float)cpn[0]
             + w1 * (float)cpn[ODIM]
             + w2 * (float)cpn[2 * ODIM]
             + w3 * (float)cpn[3 * ODIM]
             + w4 * (float)cpn[4 * ODIM];
          out[(size_t)(row0 + r) * ODIM + col] = v;
        }
      }
    }
  }
}

extern "C" void kernel_launch(void* const* d_in, const int* in_sizes, int n_in,
                              void* d_out, int out_size, void* d_ws, size_t ws_size,
                              hipStream_t stream) {
  const float* query = (const float*)d_in[0];
  const int*   cidx  = (const int*)d_in[1];
  const float* Wb    = (const float*)d_in[2];
  const float* bb    = (const float*)d_in[3];
  const float* Wc    = (const float*)d_in[4];
  const float* bc    = (const float*)d_in[5];
  const float* bkeys = (const float*)d_in[6];
  const float* bvals = (const float*)d_in[7];
  const float* ckeys = (const float*)d_in[8];
  const float* cvals = (const float*)d_in[9];
  const float* Wo    = (const float*)d_in[10];
  const float* bo    = (const float*)d_in[11];
  float* out = (float*)d_out;

  char* ws = (char*)d_ws;
  f16*   B1p   = (f16*)(ws);                        // 32768*4*2  = 262144
  f16*   B2p   = (f16*)(ws + 262144);               // 16384*4*2  = 131072
  f16*   C2cat = (f16*)(ws + 262144 + 131072);      // 175*512*2  = 179200
  float* bias1 = (float*)(ws + 262144 + 131072 + 179200);  // 1024

  k_prep<<<dim3((139008 + 255) / 256), 256, 0, stream>>>(
      Wb, bb, Wc, bc, bkeys, bvals, cvals, Wo, B1p, bias1, B2p, C2cat);
  k_fused<<<dim3(BATCH / 64), 256, 0, stream>>>(
      query, B1p, bias1, cidx, ckeys, B2p, C2cat, bo, out);
}